// Round 1
// baseline (115.774 us; speedup 1.0000x reference)
//
#include <hip/hip_runtime.h>
#include <math.h>

// BroadcastConv: out[b,o,y,x] = max_{c,i,j} ( img[b,c,y+i-2,x+j-2] + kern[o,c,4-i,4-j] )
// B=4, C=16, O=16, H=W=64, kH=kW=5, pad=2 (-inf), stride=1.
//
// Design (round 1):
//  - thread computes 4 consecutive o-channels for one (b,y,x): image value loaded
//    once, reused 4x in registers. Weight reads are wave-uniform -> scalar loads
//    (free scalar pipe, constant-cached).
//  - 65,536 threads = 1024 waves = 1 wave/SIMD across 256 CUs (min full occupancy).
//  - branchless -inf padding: clamped address + select; column masks hoisted.

#define NEG_INF (-__builtin_inff())

__global__ __launch_bounds__(256) void bconv_kernel(
        const float* __restrict__ img,
        const float* __restrict__ kern,
        float* __restrict__ out) {
    const int x  = threadIdx.x & 63;           // 0..63  (W)
    const int yl = threadIdx.x >> 6;           // 0..3
    const int y  = (blockIdx.x << 2) + yl;     // 0..63  (H)
    const int og = blockIdx.y;                 // 0..3   (o group of 4)
    const int b  = blockIdx.z;                 // 0..3

    // Per-j column index + validity: lane-dependent but loop-invariant.
    int  xc[5];
    bool xok[5];
#pragma unroll
    for (int j = 0; j < 5; ++j) {
        int xx = x + j - 2;
        xok[j] = (unsigned)xx < 64u;
        xc[j]  = xok[j] ? xx : 0;
    }

    float acc0 = NEG_INF, acc1 = NEG_INF, acc2 = NEG_INF, acc3 = NEG_INF;
    const int o0 = og * 4;

    for (int c = 0; c < 16; ++c) {
        const float* __restrict__ ic  = img  + ((b * 16 + c) * 64) * 64;
        const float* __restrict__ kc0 = kern + ((o0 + 0) * 16 + c) * 25;
        const float* __restrict__ kc1 = kern + ((o0 + 1) * 16 + c) * 25;
        const float* __restrict__ kc2 = kern + ((o0 + 2) * 16 + c) * 25;
        const float* __restrict__ kc3 = kern + ((o0 + 3) * 16 + c) * 25;
#pragma unroll
        for (int i = 0; i < 5; ++i) {
            const int  yy  = y + i - 2;
            const bool yok = (unsigned)yy < 64u;
            const float* __restrict__ rp = ic + (yok ? yy : 0) * 64;
#pragma unroll
            for (int j = 0; j < 5; ++j) {
                float v = rp[xc[j]];
                v = (yok && xok[j]) ? v : NEG_INF;
                const int ki = (4 - i) * 5 + (4 - j);   // flipped kernel index
                acc0 = fmaxf(acc0, v + kc0[ki]);
                acc1 = fmaxf(acc1, v + kc1[ki]);
                acc2 = fmaxf(acc2, v + kc2[ki]);
                acc3 = fmaxf(acc3, v + kc3[ki]);
            }
        }
    }

    const int outb = ((b * 16 + o0) * 64 + y) * 64 + x;
    out[outb         ] = acc0;
    out[outb + 4096  ] = acc1;   // one o-channel = 64*64 = 4096 elements
    out[outb + 8192  ] = acc2;
    out[outb + 12288 ] = acc3;
}

extern "C" void kernel_launch(void* const* d_in, const int* in_sizes, int n_in,
                              void* d_out, int out_size, void* d_ws, size_t ws_size,
                              hipStream_t stream) {
    const float* img  = (const float*)d_in[0];   // (4,16,64,64)
    const float* kern = (const float*)d_in[1];   // (16,16,5,5)
    float* out = (float*)d_out;                  // (4,16,64,64)
    (void)in_sizes; (void)n_in; (void)out_size; (void)d_ws; (void)ws_size;

    dim3 grid(16, 4, 4);   // y/4, o/4, b  -> 256 blocks, 1 per CU
    dim3 block(256);
    hipLaunchKernelGGL(bconv_kernel, grid, block, 0, stream, img, kern, out);
}

// Round 2
// 76.270 us; speedup vs baseline: 1.5180x; 1.5180x over previous
//
#include <hip/hip_runtime.h>
#include <math.h>

// BroadcastConv (max-plus conv): out[b,o,y,x] = max_{c,i,j} img[b,c,y+i-2,x+j-2] + kern[o,c,4-i,4-j]
// B=4, C=16, O=16, H=W=64, k=5x5, pad=2 with -inf.
//
// R2 design: block = (b, og, y); 4 waves/block, wave w reduces channels 4w..4w+3
// for 4 o's x 64 x. Partial maxes combined via small LDS tree. 1024 blocks
// -> 16 waves/CU (vs 4 in R1) for latency hiding. lane = x keeps image loads
// coalesced and all weight indices wave-uniform (scalar pipe).

#define NEG_INF (-__builtin_inff())

__global__ __launch_bounds__(256, 4) void bconv_kernel(
        const float* __restrict__ img,
        const float* __restrict__ kern,
        float* __restrict__ out) {
    const int x  = threadIdx.x & 63;   // 0..63 (W), lane id
    const int w  = threadIdx.x >> 6;   // 0..3  wave id = c-subset
    const int y  = blockIdx.x;         // 0..63
    const int og = blockIdx.y;         // 0..3
    const int b  = blockIdx.z;         // 0..3
    const int o0 = og * 4;
    const int c0 = w * 4;

    __shared__ float red[4][4][64];    // [wave][oo][x]

    // Clamped column index + validity per j (lane-dependent, loop-invariant).
    int  xc[5];
    bool xok[5];
#pragma unroll
    for (int j = 0; j < 5; ++j) {
        int xx = x + j - 2;
        xok[j] = (unsigned)xx < 64u;
        xc[j]  = xok[j] ? xx : 0;
    }

    float acc0 = NEG_INF, acc1 = NEG_INF, acc2 = NEG_INF, acc3 = NEG_INF;

#pragma unroll
    for (int cc = 0; cc < 4; ++cc) {
        const int c = c0 + cc;
        const float* __restrict__ ic = img + ((b * 16 + c) << 12);   // 64*64 plane
        const float* __restrict__ k0 = kern + ((o0 + 0) * 16 + c) * 25;
        const float* __restrict__ k1 = kern + ((o0 + 1) * 16 + c) * 25;
        const float* __restrict__ k2 = kern + ((o0 + 2) * 16 + c) * 25;
        const float* __restrict__ k3 = kern + ((o0 + 3) * 16 + c) * 25;
#pragma unroll
        for (int i = 0; i < 5; ++i) {
            const int yy = y + i - 2;
            if ((unsigned)yy >= 64u) continue;   // wave-uniform row skip (-inf rows)
            const float* __restrict__ rp = ic + (yy << 6);
            // Batch the 5 column loads (independent -> in flight together).
            float v[5];
#pragma unroll
            for (int j = 0; j < 5; ++j) {
                float t = rp[xc[j]];
                v[j] = xok[j] ? t : NEG_INF;
            }
            const int kb = (4 - i) * 5 + 4;      // ki = kb - j
            // Pair taps so compiler can emit v_max3_f32.
#define ACC_O(kp, A)                                            \
            {                                                   \
                float t0 = v[0] + kp[kb - 0];                   \
                float t1 = v[1] + kp[kb - 1];                   \
                float t2 = v[2] + kp[kb - 2];                   \
                float t3 = v[3] + kp[kb - 3];                   \
                float t4 = v[4] + kp[kb - 4];                   \
                A = fmaxf(A, fmaxf(t0, t1));                    \
                A = fmaxf(A, fmaxf(t2, t3));                    \
                A = fmaxf(A, t4);                               \
            }
            ACC_O(k0, acc0)
            ACC_O(k1, acc1)
            ACC_O(k2, acc2)
            ACC_O(k3, acc3)
#undef ACC_O
        }
    }

    // Cross-wave max reduction through LDS.
    red[w][0][x] = acc0;
    red[w][1][x] = acc1;
    red[w][2][x] = acc2;
    red[w][3][x] = acc3;
    __syncthreads();

    // 256 threads -> 256 outputs: thread t = (oo = t>>6, x = t&63).
    const int oo = threadIdx.x >> 6;
    float r = fmaxf(fmaxf(red[0][oo][x], red[1][oo][x]),
                    fmaxf(red[2][oo][x], red[3][oo][x]));
    out[(((b * 16 + o0 + oo) << 6) + y) * 64 + x] = r;
}

extern "C" void kernel_launch(void* const* d_in, const int* in_sizes, int n_in,
                              void* d_out, int out_size, void* d_ws, size_t ws_size,
                              hipStream_t stream) {
    const float* img  = (const float*)d_in[0];   // (4,16,64,64)
    const float* kern = (const float*)d_in[1];   // (16,16,5,5)
    float* out = (float*)d_out;                  // (4,16,64,64)
    (void)in_sizes; (void)n_in; (void)out_size; (void)d_ws; (void)ws_size;

    dim3 grid(64, 4, 4);   // y, o/4, b -> 1024 blocks, 4 waves each
    dim3 block(256);
    hipLaunchKernelGGL(bconv_kernel, grid, block, 0, stream, img, kern, out);
}

// Round 3
// 66.397 us; speedup vs baseline: 1.7437x; 1.1487x over previous
//
#include <hip/hip_runtime.h>
#include <math.h>

// BroadcastConv (max-plus conv): out[b,o,y,x] = max_{c,i,j} img[b,c,y+i-2,x+j-2] + kern[o,c,4-i,4-j]
// B=4, C=16, O=16, H=W=64, k=5x5, pad=2 with -inf.
//
// R3: (1) weights through the SCALAR pipe — wave id made uniform via
// readfirstlane so weight addresses are provably wave-uniform -> s_load
// (R2 issued 400 vector weight loads/thread = the real bottleneck);
// (2) image pre-padded to 68x68 with -inf by a cheap pad kernel into d_ws ->
// no masks, straight-line unrolled loads in big hoistable bursts;
// (3) same 4-wave c-split + LDS max-reduce as R2.

#define NEG_INF (-__builtin_inff())

#define PW 68
#define PPLANE (PW * PW)   // 4624

__global__ __launch_bounds__(256) void pad_kernel(
        const float* __restrict__ img, float* __restrict__ pad) {
    const int idx   = blockIdx.x * 256 + threadIdx.x;   // 0 .. 295935
    const int plane = idx / PPLANE;                     // 0..63  (b*16+c)
    const int rem   = idx % PPLANE;
    const int py    = rem / PW;
    const int px    = rem % PW;
    const int yy = py - 2, xx = px - 2;
    float v = NEG_INF;
    if ((unsigned)yy < 64u && (unsigned)xx < 64u)
        v = img[(plane << 12) + (yy << 6) + xx];
    pad[idx] = v;
}

__global__ __launch_bounds__(256, 4) void bconv_kernel(
        const float* __restrict__ pad,
        const float* __restrict__ kern,
        float* __restrict__ out) {
    const int x  = threadIdx.x & 63;                                   // lane = W
    const int w  = __builtin_amdgcn_readfirstlane(threadIdx.x >> 6);   // wave id, UNIFORM
    const int y  = blockIdx.x;
    const int og = blockIdx.y;
    const int b  = blockIdx.z;
    const int o0 = og * 4;
    const int c0 = w * 4;

    __shared__ float red[4][4][64];

    float acc0 = NEG_INF, acc1 = NEG_INF, acc2 = NEG_INF, acc3 = NEG_INF;

#pragma unroll
    for (int cc = 0; cc < 4; ++cc) {
        const int c = c0 + cc;
        // Padded plane: output y, tap i -> padded row y+i; col x, tap j -> x+j.
        const float* __restrict__ pl = pad + (b * 16 + c) * PPLANE + y * PW + x;

        // 25 independent image loads (one burst).
        float v[25];
#pragma unroll
        for (int i = 0; i < 5; ++i)
#pragma unroll
            for (int j = 0; j < 5; ++j)
                v[i * 5 + j] = pl[i * PW + j];

        // Weight for tap t=(i*5+j) is kern[o][c][24-t] (the double flip).
#define ACC_O(oo, A)                                                     \
        {                                                                \
            const float* __restrict__ kp = kern + ((o0 + oo) * 16 + c) * 25; \
            float kw[25];                                                \
            _Pragma("unroll")                                            \
            for (int t = 0; t < 25; ++t) kw[t] = kp[t];                  \
            _Pragma("unroll")                                            \
            for (int g = 0; g < 5; ++g) {                                \
                float t0 = v[g * 5 + 0] + kw[24 - (g * 5 + 0)];          \
                float t1 = v[g * 5 + 1] + kw[24 - (g * 5 + 1)];          \
                float t2 = v[g * 5 + 2] + kw[24 - (g * 5 + 2)];          \
                float t3 = v[g * 5 + 3] + kw[24 - (g * 5 + 3)];          \
                float t4 = v[g * 5 + 4] + kw[24 - (g * 5 + 4)];          \
                A = fmaxf(A, fmaxf(t0, t1));                             \
                A = fmaxf(A, fmaxf(t2, t3));                             \
                A = fmaxf(A, t4);                                        \
            }                                                            \
        }
        ACC_O(0, acc0)
        ACC_O(1, acc1)
        ACC_O(2, acc2)
        ACC_O(3, acc3)
#undef ACC_O
    }

    // Cross-wave max reduction (each wave covered 4 of 16 channels).
    red[w][0][x] = acc0;
    red[w][1][x] = acc1;
    red[w][2][x] = acc2;
    red[w][3][x] = acc3;
    __syncthreads();

    const int oo = threadIdx.x >> 6;
    float r = fmaxf(fmaxf(red[0][oo][x], red[1][oo][x]),
                    fmaxf(red[2][oo][x], red[3][oo][x]));
    out[(((b * 16 + o0 + oo) << 6) + y) * 64 + x] = r;
}

extern "C" void kernel_launch(void* const* d_in, const int* in_sizes, int n_in,
                              void* d_out, int out_size, void* d_ws, size_t ws_size,
                              hipStream_t stream) {
    const float* img  = (const float*)d_in[0];   // (4,16,64,64)
    const float* kern = (const float*)d_in[1];   // (16,16,5,5)
    float* out = (float*)d_out;                  // (4,16,64,64)
    float* pad = (float*)d_ws;                   // (4*16, 68, 68) = 1.18 MB
    (void)in_sizes; (void)n_in; (void)out_size; (void)ws_size;

    // 64 planes * 4624 = 295936 = 1156 * 256 exactly.
    hipLaunchKernelGGL(pad_kernel, dim3(1156), dim3(256), 0, stream, img, pad);

    dim3 grid(64, 4, 4);   // y, o/4, b
    hipLaunchKernelGGL(bconv_kernel, grid, dim3(256), 0, stream, pad, kern, out);
}

// Round 4
// 65.731 us; speedup vs baseline: 1.7613x; 1.0101x over previous
//
#include <hip/hip_runtime.h>
#include <math.h>

// BroadcastConv (max-plus conv): out[b,o,y,x] = max_{c,i,j} img[b,c,y+i-2,x+j-2] + kern[o,c,4-i,4-j]
// B=4, C=16, O=16, H=W=64, k=5x5, pad=2 with -inf.
//
// R4: (1) 512-thread blocks, 8 waves, c-split 8-way (2 c/wave) -> 32 waves/CU
//     (max occupancy; R3 had 16) for latency hiding;
// (2) each lane's 5-tap window loaded as one unaligned dwordx4 + dword ->
//     20 VMEM insts/wave instead of 100;
// (3) packed f32x2 adds (v_pk_add_f32) + max3 trees;
// (4) weights stay on the scalar pipe (readfirstlane-uniform wave id);
// (5) pad kernel vectorized to float4 stores.

#define NEG_INF (-__builtin_inff())
#define PW 68
#define PPLANE (PW * PW)   // 4624

typedef float f32x2  __attribute__((ext_vector_type(2)));
typedef float f32x4u __attribute__((ext_vector_type(4), aligned(4)));

__global__ __launch_bounds__(256) void pad_kernel(
        const float* __restrict__ img, float* __restrict__ pad) {
    const int idx4  = blockIdx.x * 256 + threadIdx.x;   // 0..73983 (64 planes * 1156 float4)
    const int plane = idx4 / 1156;                      // PPLANE/4
    const int r4    = idx4 - plane * 1156;
    const int py    = r4 / 17;                          // PW/4
    const int px0   = (r4 - py * 17) * 4;
    const int yy    = py - 2;
    const bool yok  = (unsigned)yy < 64u;
    const float* src = img + (plane << 12) + ((yok ? yy : 0) << 6);
    float o[4];
#pragma unroll
    for (int t = 0; t < 4; ++t) {
        int xx = px0 + t - 2;
        bool ok = yok && ((unsigned)xx < 64u);
        o[t] = ok ? src[(unsigned)xx < 64u ? xx : 0] : NEG_INF;
    }
    float4* dst = (float4*)(pad + plane * PPLANE + py * PW + px0);
    *dst = make_float4(o[0], o[1], o[2], o[3]);
}

__global__ __launch_bounds__(512, 8) void bconv_kernel(
        const float* __restrict__ pad,
        const float* __restrict__ kern,
        float* __restrict__ out) {
    const int x  = threadIdx.x & 63;                                   // lane = W
    const int w  = __builtin_amdgcn_readfirstlane(threadIdx.x >> 6);   // wave id 0..7, UNIFORM
    const int y  = blockIdx.x;
    const int og = blockIdx.y;
    const int b  = blockIdx.z;
    const int o0 = og * 4;
    const int c0 = w * 2;

    __shared__ float red[8][4][64];

    float acc0 = NEG_INF, acc1 = NEG_INF, acc2 = NEG_INF, acc3 = NEG_INF;

#pragma unroll 1                       // keep the two c-iterations serial: VGPR cap 64
    for (int cc = 0; cc < 2; ++cc) {
        const int c = c0 + cc;
        const float* __restrict__ pl = pad + (b * 16 + c) * PPLANE + y * PW + x;

        // 5 rows x 5 taps; per row: one unaligned dwordx4 + one dword.
        float v[5][5];
#pragma unroll
        for (int i = 0; i < 5; ++i) {
            f32x4u v4 = *(const f32x4u*)(pl + i * PW);
            v[i][0] = v4.x; v[i][1] = v4.y; v[i][2] = v4.z; v[i][3] = v4.w;
            v[i][4] = pl[i * PW + 4];
        }

        // tap t = i*5+j pairs with kern[o][c][24-t] (double flip).
#define ACC_O(oo, A)                                                          \
        {                                                                     \
            const float* __restrict__ kp = kern + ((o0 + oo) * 16 + c) * 25;  \
            _Pragma("unroll")                                                 \
            for (int g = 0; g < 5; ++g) {                                     \
                const int kb = 24 - g * 5;                                    \
                f32x2 a01 = (f32x2){v[g][0], v[g][1]}                         \
                          + (f32x2){kp[kb], kp[kb - 1]};                      \
                f32x2 a23 = (f32x2){v[g][2], v[g][3]}                         \
                          + (f32x2){kp[kb - 2], kp[kb - 3]};                  \
                float a4  = v[g][4] + kp[kb - 4];                             \
                float m01 = fmaxf(a01.x, a01.y);                              \
                float m234 = fmaxf(fmaxf(a23.x, a23.y), a4);                  \
                A = fmaxf(A, fmaxf(m01, m234));                               \
            }                                                                 \
        }
        ACC_O(0, acc0)
        ACC_O(1, acc1)
        ACC_O(2, acc2)
        ACC_O(3, acc3)
#undef ACC_O
    }

    // Cross-wave max reduction (each wave covered 2 of 16 channels).
    red[w][0][x] = acc0;
    red[w][1][x] = acc1;
    red[w][2][x] = acc2;
    red[w][3][x] = acc3;
    __syncthreads();

    if (threadIdx.x < 256) {
        const int oo = threadIdx.x >> 6;
        float r = red[0][oo][x];
#pragma unroll
        for (int ww = 1; ww < 8; ++ww) r = fmaxf(r, red[ww][oo][x]);
        out[((b * 16 + o0 + oo) << 12) + (y << 6) + x] = r;
    }
}

extern "C" void kernel_launch(void* const* d_in, const int* in_sizes, int n_in,
                              void* d_out, int out_size, void* d_ws, size_t ws_size,
                              hipStream_t stream) {
    const float* img  = (const float*)d_in[0];   // (4,16,64,64)
    const float* kern = (const float*)d_in[1];   // (16,16,5,5)
    float* out = (float*)d_out;                  // (4,16,64,64)
    float* pad = (float*)d_ws;                   // (64, 68, 68) floats = 1.18 MB
    (void)in_sizes; (void)n_in; (void)out_size; (void)ws_size;

    // 64 planes * 1156 float4 = 73984 threads = 289 * 256.
    hipLaunchKernelGGL(pad_kernel, dim3(289), dim3(256), 0, stream, img, pad);

    dim3 grid(64, 4, 4);   // y, o/4, b -> 1024 blocks * 8 waves = 32 waves/CU
    hipLaunchKernelGGL(bconv_kernel, grid, dim3(512), 0, stream, pad, kern, out);
}